// Round 2
// baseline (53.678 us; speedup 1.0000x reference)
//
#include <hip/hip_runtime.h>

// Segmented histogram: out[g, c] = sum of node_weights[i] for i in
// [ptr[g], ptr[g+1]) with x[i] == c, for c < out_dim.
//
// One block per graph. LDS histogram + LDS atomics. Node stream is read
// 4-wide (int4 labels / float4 weights) with scalar head/tail to handle
// unaligned segment boundaries.

extern "C" __global__ __launch_bounds__(256)
void seg_hist_kernel(const int* __restrict__ x,
                     const int* __restrict__ ptr,
                     const float* __restrict__ w,
                     float* __restrict__ out,
                     int out_dim) {
    extern __shared__ float hist[];  // out_dim floats

    const int g = blockIdx.x;
    const int start = ptr[g];
    const int end = ptr[g + 1];
    const int tid = (int)threadIdx.x;

    // zero the LDS histogram
    for (int c = tid; c < out_dim; c += 256) hist[c] = 0.0f;
    __syncthreads();

    // ---- alignment split: head [start,aStart) | body [aStart,aEnd) | tail [aEnd,end)
    const int aStart0 = (start + 3) & ~3;
    const int aStart = (aStart0 < end) ? aStart0 : end;
    int aEnd = end & ~3;
    if (aEnd < aStart) aEnd = aStart;

    // head (<=3 elements)
    {
        const int i = start + tid;
        if (i < aStart) {
            const int lbl = x[i];
            if ((unsigned)lbl < (unsigned)out_dim) atomicAdd(&hist[lbl], w[i]);
        }
    }

    // body: 4 nodes per thread per iteration, 16B-aligned vector loads
    for (int i = aStart + tid * 4; i < aEnd; i += 256 * 4) {
        const int4   l4 = *reinterpret_cast<const int4*>(x + i);
        const float4 w4 = *reinterpret_cast<const float4*>(w + i);
        if ((unsigned)l4.x < (unsigned)out_dim) atomicAdd(&hist[l4.x], w4.x);
        if ((unsigned)l4.y < (unsigned)out_dim) atomicAdd(&hist[l4.y], w4.y);
        if ((unsigned)l4.z < (unsigned)out_dim) atomicAdd(&hist[l4.z], w4.z);
        if ((unsigned)l4.w < (unsigned)out_dim) atomicAdd(&hist[l4.w], w4.w);
    }

    // tail (<=3 elements)
    {
        const int i = aEnd + tid;
        if (i < end) {
            const int lbl = x[i];
            if ((unsigned)lbl < (unsigned)out_dim) atomicAdd(&hist[lbl], w[i]);
        }
    }

    __syncthreads();

    // coalesced row write (1 KB per block)
    float* o = out + (size_t)g * (size_t)out_dim;
    for (int c = tid; c < out_dim; c += 256) o[c] = hist[c];
}

extern "C" void kernel_launch(void* const* d_in, const int* in_sizes, int n_in,
                              void* d_out, int out_size, void* d_ws, size_t ws_size,
                              hipStream_t stream) {
    const int* x   = (const int*)d_in[0];
    const int* ptr = (const int*)d_in[1];
    const float* w = (const float*)d_in[2];
    float* out     = (float*)d_out;

    const int num_graphs = in_sizes[1] - 1;          // ptr has num_graphs+1 entries
    const int out_dim    = out_size / num_graphs;    // 256

    dim3 grid(num_graphs);
    dim3 block(256);
    size_t lds_bytes = (size_t)out_dim * sizeof(float);

    seg_hist_kernel<<<grid, block, lds_bytes, stream>>>(x, ptr, w, out, out_dim);
}